// Round 16
// baseline (320.303 us; speedup 1.0000x reference)
//
#include <hip/hip_runtime.h>

#define L 4096
#define D 512
#define NCH 16   // context n-chunks (256 n per chunk)

typedef __bf16 bf16x8 __attribute__((ext_vector_type(8)));
typedef float  f32x4  __attribute__((ext_vector_type(4)));

__device__ __forceinline__ void load_lds16(const void* g, void* l) {
    __builtin_amdgcn_global_load_lds(
        (const __attribute__((address_space(1))) void*)g,
        (__attribute__((address_space(3))) void*)l, 16, 0, 0);
}

__device__ __forceinline__ void barrier_mem() {
    asm volatile("" ::: "memory");
    __builtin_amdgcn_s_barrier();
    asm volatile("" ::: "memory");
}

// ---------------------------------------------------------------------------
// 256x256-tile TN MFMA GEMM, WAVE-SLIP schedule, with IN-KERNEL f32->bf16
// operand conversion (replaces the standalone convert_all kernel; R15
// accounting: ~115us of pipeline time sits outside GEMM compute — kill a
// launch + 100MB of convert traffic instead of chasing GEMM micro-gains).
// Operand staging by type:
//  bf16: global_load_lds (vmcnt-class), depth 1 (issue@kt for tile kt+1).
//  f32 : reg-staged depth 2 — float4 loads @kt for tile kt+2; cvt+ds_write
//        @kt for tile kt+1 (regs from kt-1); read @kt+1.
// Cascade thresholds UNCHANGED: the W ds_writes issued at body start are
// OLDEST in the in-order lgkm queue, so lgkm(4/8/4/0) drain them before the
// counted reads; global_load_lds never touches lgkm.
// Hazards: prologue writes drained by explicit lgkm(0) before body-0
// barrier; steady-state writes retire at each body's final lgkm(0) (pre-
// barrier); WAR on LDS buf p^1 (write@kt) ordered behind kt-1's readers'
// lgkm(0) + barrier@kt; vmcnt(0)@kt drains tile-kt gloads + tile-kt+1 reg
// loads (both issued @kt-1, ~1 body of cover).
// ---------------------------------------------------------------------------
template <int M, int N, int K, typename AT, typename BT, typename CT>
__global__ __launch_bounds__(512, 2) void gemm_ws2(
    const AT* __restrict__ A, size_t aStride,
    const BT* __restrict__ B, size_t bStride,
    CT* __restrict__ C, size_t cStride,
    const float* __restrict__ bias) {
    constexpr bool AF = (sizeof(AT) == 4);   // A is f32 (reg-staged)
    constexpr bool BF = (sizeof(BT) == 4);   // B is f32 (reg-staged)
    __shared__ __align__(16) __bf16 sB[2][256 * 64];   // 64 KB
    __shared__ __align__(16) __bf16 sA[2][256 * 64];   // 64 KB
    constexpr int NT = K / 64;                          // 8
    const int b  = blockIdx.z;
    const int m0 = blockIdx.y * 256;
    const int n0 = blockIdx.x * 256;
    const int t    = threadIdx.x;
    const int wave = t >> 6, lane = t & 63;
    const int wm = (wave >> 2) * 128;   // 2 M-halves
    const int wn = (wave & 3) * 64;     // 4 N-quads
    const int fr = lane & 15, g = lane >> 4;
    const AT* Ab = A + (size_t)b * aStride + (size_t)m0 * K;
    const BT* Bb = B + (size_t)b * bStride + (size_t)n0 * K;
    CT* Cb = C + (size_t)b * cStride;

    const AT* pA_[4];
    const BT* pB_[4];
#pragma unroll
    for (int k = 0; k < 4; ++k) {
        const int gi = k * 512 + t, row = gi >> 3, cc = gi & 7;
        pA_[k] = Ab + (size_t)row * K + (cc ^ (row & 7)) * 8;
        pB_[k] = Bb + (size_t)row * K + (cc ^ (row & 7)) * 8;
    }
    const int lc0 = ((0 + g) ^ (fr & 7)) * 8;
    const int lc1 = ((4 + g) ^ (fr & 7)) * 8;

    f32x4 acc[8][4];
#pragma unroll
    for (int i = 0; i < 8; i++)
#pragma unroll
        for (int j = 0; j < 4; j++) acc[i][j] = (f32x4)(0.0f);

    float4 rA[4][2], rB[4][2];   // live only for f32 operands

    auto loadA_f32 = [&](int kt) {
        if constexpr (AF) {
#pragma unroll
            for (int k = 0; k < 4; ++k) {
                rA[k][0] = *(const float4*)(pA_[k] + kt * 64);
                rA[k][1] = *(const float4*)(pA_[k] + kt * 64 + 4);
            }
        }
    };
    auto loadB_f32 = [&](int kt) {
        if constexpr (BF) {
#pragma unroll
            for (int k = 0; k < 4; ++k) {
                rB[k][0] = *(const float4*)(pB_[k] + kt * 64);
                rB[k][1] = *(const float4*)(pB_[k] + kt * 64 + 4);
            }
        }
    };
    auto loadA_lds = [&](int kt) {
        if constexpr (!AF) {
#pragma unroll
            for (int k = 0; k < 4; ++k)
                load_lds16(pA_[k] + kt * 64, &sA[kt & 1][(k * 512 + t) * 8]);
        }
    };
    auto loadB_lds = [&](int kt) {
        if constexpr (!BF) {
#pragma unroll
            for (int k = 0; k < 4; ++k)
                load_lds16(pB_[k] + kt * 64, &sB[kt & 1][(k * 512 + t) * 8]);
        }
    };
    auto cvt8 = [](float4 a, float4 c) -> bf16x8 {
        return bf16x8{(__bf16)a.x, (__bf16)a.y, (__bf16)a.z, (__bf16)a.w,
                      (__bf16)c.x, (__bf16)c.y, (__bf16)c.z, (__bf16)c.w};
    };
    auto writeA = [&](int pb) {
        if constexpr (AF) {
#pragma unroll
            for (int k = 0; k < 4; ++k)
                *(bf16x8*)&sA[pb][(k * 512 + t) * 8] = cvt8(rA[k][0], rA[k][1]);
        }
    };
    auto writeB = [&](int pb) {
        if constexpr (BF) {
#pragma unroll
            for (int k = 0; k < 4; ++k)
                *(bf16x8*)&sB[pb][(k * 512 + t) * 8] = cvt8(rB[k][0], rB[k][1]);
        }
    };

    // prologue: tile 0 (f32->regs / bf16->gload buf0), then write f32 parts
    loadA_f32(0); loadB_f32(0);
    loadA_lds(0); loadB_lds(0);
    if constexpr (AF || BF) {
        asm volatile("s_waitcnt vmcnt(0)" ::: "memory");
        writeA(0); writeB(0);
        asm volatile("s_waitcnt lgkmcnt(0)" ::: "memory");  // writes visible pre-barrier
        loadA_f32(1); loadB_f32(1);                         // tile1 regs for body0
    }

#pragma unroll
    for (int kt = 0; kt < NT; ++kt) {
        const int p = kt & 1;
        asm volatile("s_waitcnt vmcnt(0)" ::: "memory");   // tile kt staged + kt+1 regs
        barrier_mem();                                     // single barrier/K-tile
        if (kt + 1 < NT) { writeA(p ^ 1); writeB(p ^ 1); } // f32 tile kt+1 -> LDS
        if (kt + 2 < NT) { loadA_f32(kt + 2); loadB_f32(kt + 2); }
        if (kt + 1 < NT) { loadA_lds(kt + 1); loadB_lds(kt + 1); }

        bf16x8 fB0[4], fB1[4], fA0[4], fA1[4], fA2[4], fA3[4];
        // group 1: B0, A0, A1 (12 reads; any stage ds_writes are older)
#pragma unroll
        for (int j = 0; j < 4; ++j)
            fB0[j] = *(const bf16x8*)&sB[p][(wn + j * 16 + fr) * 64 + lc0];
#pragma unroll
        for (int i = 0; i < 4; ++i)
            fA0[i] = *(const bf16x8*)&sA[p][(wm + i * 16 + fr) * 64 + lc0];
#pragma unroll
        for (int i = 0; i < 4; ++i)
            fA1[i] = *(const bf16x8*)&sA[p][(wm + 64 + i * 16 + fr) * 64 + lc0];
        asm volatile("s_waitcnt lgkmcnt(4)" ::: "memory");  // writes+B0+A0 done, A1 out
        __builtin_amdgcn_sched_barrier(0);
        __builtin_amdgcn_s_setprio(1);
#pragma unroll
        for (int i = 0; i < 4; ++i)
#pragma unroll
            for (int j = 0; j < 4; ++j)
                acc[i][j] = __builtin_amdgcn_mfma_f32_16x16x32_bf16(fA0[i], fB0[j], acc[i][j], 0, 0, 0);
        __builtin_amdgcn_s_setprio(0);
        // group 2: B1, A2 issued; A1's MFMA runs while they retire
#pragma unroll
        for (int j = 0; j < 4; ++j)
            fB1[j] = *(const bf16x8*)&sB[p][(wn + j * 16 + fr) * 64 + lc1];
#pragma unroll
        for (int i = 0; i < 4; ++i)
            fA2[i] = *(const bf16x8*)&sA[p][(wm + i * 16 + fr) * 64 + lc1];
        asm volatile("s_waitcnt lgkmcnt(8)" ::: "memory");  // A1 done (in-order)
        __builtin_amdgcn_sched_barrier(0);
        __builtin_amdgcn_s_setprio(1);
#pragma unroll
        for (int i = 0; i < 4; ++i)
#pragma unroll
            for (int j = 0; j < 4; ++j)
                acc[4 + i][j] = __builtin_amdgcn_mfma_f32_16x16x32_bf16(fA1[i], fB0[j], acc[4 + i][j], 0, 0, 0);
        __builtin_amdgcn_s_setprio(0);
        // group 3: A3 issued under A2's MFMA
#pragma unroll
        for (int i = 0; i < 4; ++i)
            fA3[i] = *(const bf16x8*)&sA[p][(wm + 64 + i * 16 + fr) * 64 + lc1];
        asm volatile("s_waitcnt lgkmcnt(4)" ::: "memory");  // B1+A2 done, A3 out
        __builtin_amdgcn_sched_barrier(0);
        __builtin_amdgcn_s_setprio(1);
#pragma unroll
        for (int i = 0; i < 4; ++i)
#pragma unroll
            for (int j = 0; j < 4; ++j)
                acc[i][j] = __builtin_amdgcn_mfma_f32_16x16x32_bf16(fA2[i], fB1[j], acc[i][j], 0, 0, 0);
        __builtin_amdgcn_s_setprio(0);
        asm volatile("s_waitcnt lgkmcnt(0)" ::: "memory");  // A3 done (+ all writes)
        __builtin_amdgcn_sched_barrier(0);
        __builtin_amdgcn_s_setprio(1);
#pragma unroll
        for (int i = 0; i < 4; ++i)
#pragma unroll
            for (int j = 0; j < 4; ++j)
                acc[4 + i][j] = __builtin_amdgcn_mfma_f32_16x16x32_bf16(fA3[i], fB1[j], acc[4 + i][j], 0, 0, 0);
        __builtin_amdgcn_s_setprio(0);
    }

    // epilogue: j-innermost so adjacent 32B chunks issue back-to-back
    const int rb = g * 4;
    float bv[4];
#pragma unroll
    for (int j = 0; j < 4; ++j) bv[j] = bias ? bias[n0 + wn + j * 16 + fr] : 0.0f;
#pragma unroll
    for (int i = 0; i < 8; ++i) {
#pragma unroll
        for (int r = 0; r < 4; ++r) {
            const int m = m0 + wm + i * 16 + rb + r;
            CT* rowp = Cb + (size_t)m * N + n0 + wn + fr;
#pragma unroll
            for (int j = 0; j < 4; ++j)
                rowp[j * 16] = (CT)(acc[i][j][r] + bv[j]);
        }
    }
}

// ---------------------------------------------------------------------------
// context_local: per (chunk,bh) block computes LOCAL k-row max/sumexp and
// un-normalized partial ctxp (no cross-block sync; kernel boundary orders).
// ---------------------------------------------------------------------------
#define SKS 264   // LDS bf16 row stride (256 data + 8 pad)
__global__ __launch_bounds__(256) void context_local(const __bf16* __restrict__ qkv,
                                                     float* __restrict__ ctxp,
                                                     float* __restrict__ mstat,
                                                     float* __restrict__ sstat) {
    __shared__ __align__(16) __bf16 smem[2 * 64 * SKS];  // 67.6 KB; reused as f32 red[4][4096]
    __bf16* sk = smem;
    __bf16* sv = smem + 64 * SKS;
    const int chunk = blockIdx.x;
    const int bh = blockIdx.y;
    const int b = bh >> 3, h = bh & 7;
    const __bf16* kbase = qkv + (size_t)b * 1536 * L + (size_t)(512 + h * 64) * L;
    const __bf16* vbase = qkv + (size_t)b * 1536 * L + (size_t)(1024 + h * 64) * L;
    const int t = threadIdx.x;

    {
        const int d = t >> 2, noff = (t & 3) * 64;
        const int n0 = chunk * 256;
        const __bf16* kp = kbase + (size_t)d * L + n0 + noff;
        const __bf16* vp = vbase + (size_t)d * L + n0 + noff;
        bf16x8 kk[8];
        float m = -1e30f;
#pragma unroll
        for (int c = 0; c < 8; c++) {
            kk[c] = *(const bf16x8*)(kp + c * 8);
            bf16x8 vv = *(const bf16x8*)(vp + c * 8);
            *(bf16x8*)&sv[d * SKS + noff + c * 8] = vv;
#pragma unroll
            for (int j = 0; j < 8; j++) m = fmaxf(m, (float)kk[c][j]);
        }
        m = fmaxf(m, __shfl_xor(m, 1, 64));
        m = fmaxf(m, __shfl_xor(m, 2, 64));
        float s = 0.f;
#pragma unroll
        for (int c = 0; c < 8; c++) {
            bf16x8 ek;
#pragma unroll
            for (int j = 0; j < 8; j++) {
                float e = __expf((float)kk[c][j] - m);
                s += e;
                ek[j] = (__bf16)e;
            }
            *(bf16x8*)&sk[d * SKS + noff + c * 8] = ek;
        }
        s += __shfl_xor(s, 1, 64);
        s += __shfl_xor(s, 2, 64);
        if ((t & 3) == 0) {
            mstat[((size_t)chunk * 64 + bh) * 64 + d] = m;
            sstat[((size_t)chunk * 64 + bh) * 64 + d] = s;
        }
    }
    __syncthreads();

    const int wave = t >> 6, lane = t & 63;
    const int fr = lane & 15, kq = (lane >> 4) * 8;
    f32x4 acc[4][4];
#pragma unroll
    for (int i = 0; i < 4; i++)
#pragma unroll
        for (int j = 0; j < 4; j++) acc[i][j] = (f32x4)(0.0f);
#pragma unroll
    for (int kh = 0; kh < 2; kh++) {
        const int koff = wave * 64 + kh * 32 + kq;
        bf16x8 af[4], bfr[4];
#pragma unroll
        for (int i = 0; i < 4; i++) {
            af[i]  = *(const bf16x8*)&sk[(i * 16 + fr) * SKS + koff];
            bfr[i] = *(const bf16x8*)&sv[(i * 16 + fr) * SKS + koff];
        }
#pragma unroll
        for (int i = 0; i < 4; i++)
#pragma unroll
            for (int j = 0; j < 4; j++)
                acc[i][j] = __builtin_amdgcn_mfma_f32_16x16x32_bf16(af[i], bfr[j], acc[i][j], 0, 0, 0);
    }
    __syncthreads();

    float* red = (float*)smem;
    const int col = lane & 15, rbase = (lane >> 4) * 4;
#pragma unroll
    for (int i = 0; i < 4; i++)
#pragma unroll
        for (int j = 0; j < 4; j++)
#pragma unroll
            for (int r = 0; r < 4; r++) {
                const int dd = i * 16 + rbase + r;
                const int ee = j * 16 + col;
                red[wave * 4096 + dd * 64 + ee] = acc[i][j][r];
            }
    __syncthreads();
    float* cp = ctxp + ((size_t)chunk * 64 + bh) * 4096;
#pragma unroll
    for (int gg = 0; gg < 4; gg++) {
        const int idx = t * 16 + gg * 4;
        f32x4 s = *(const f32x4*)&red[idx];
        s += *(const f32x4*)&red[4096 + idx];
        s += *(const f32x4*)&red[8192 + idx];
        s += *(const f32x4*)&red[12288 + idx];
        *(f32x4*)&cp[idx] = s;
    }
}

// ---------------------------------------------------------------------------
// ctx_combine: online-softmax combine across chunks; transpose to bf16 ctxT.
// ---------------------------------------------------------------------------
__global__ __launch_bounds__(256) void ctx_combine(const float* __restrict__ ctxp,
                                                   const float* __restrict__ mstat,
                                                   const float* __restrict__ sstat,
                                                   __bf16* __restrict__ ctxT) {
    const int bh = blockIdx.x >> 2, quarter = blockIdx.x & 3;
    const int t = threadIdx.x;
    const int flat = quarter * 1024 + t * 4;
    const int d = flat >> 6, e0 = flat & 63;
    float M = -1e30f;
#pragma unroll
    for (int ch = 0; ch < NCH; ch++)
        M = fmaxf(M, mstat[((size_t)ch * 64 + bh) * 64 + d]);
    float S = 0.f;
    float w[NCH];
#pragma unroll
    for (int ch = 0; ch < NCH; ch++) {
        w[ch] = __expf(mstat[((size_t)ch * 64 + bh) * 64 + d] - M);
        S += sstat[((size_t)ch * 64 + bh) * 64 + d] * w[ch];
    }
    const float inv = 1.0f / S;
    f32x4 s = (f32x4)(0.0f);
#pragma unroll
    for (int ch = 0; ch < NCH; ch++) {
        f32x4 v = *(const f32x4*)&ctxp[((size_t)ch * 64 + bh) * 4096 + flat];
        s += v * w[ch];
    }
    __bf16* o = ctxT + (size_t)bh * 4096;
#pragma unroll
    for (int j = 0; j < 4; j++) o[(e0 + j) * 64 + d] = (__bf16)(s[j] * inv);
}

// ---------------------------------------------------------------------------
// pv_fused: per (bh, 256-col tile): q-softmax + MFMA vs ctxT -> bf16 outT.
// ---------------------------------------------------------------------------
#define SPS 66   // LDS row stride (bf16)
__global__ __launch_bounds__(256) void pv_fused(__bf16* __restrict__ qkv,
                                                const __bf16* __restrict__ ctxT) {
    __shared__ __align__(16) __bf16 sp[256 * SPS];
    __shared__ __align__(16) __bf16 sctx[64 * SPS];
    __shared__ float sinv[256];
    const int tileN = blockIdx.x;
    const int bh = blockIdx.y;
    const int b = bh >> 3, h = bh & 7;
    const int t = threadIdx.x;
    const int n0 = tileN * 256;
    const __bf16* qbase = qkv + (size_t)b * 1536 * L + (size_t)(h * 64) * L;

    {
        const int e = t >> 2, c = t & 3;
        const bf16x8* src = (const bf16x8*)(ctxT + ((size_t)bh * 64 + e) * 64 + c * 16);
        *(bf16x8*)&sctx[e * SPS + c * 16] = src[0];
        *(bf16x8*)&sctx[e * SPS + c * 16 + 8] = src[1];
    }

    float m = -1e30f;
    float qv[64];
#pragma unroll
    for (int d = 0; d < 64; d++) {
        qv[d] = (float)qbase[(size_t)d * L + n0 + t];
        m = fmaxf(m, qv[d]);
    }
    float s = 0.f;
#pragma unroll
    for (int d0 = 0; d0 < 64; d0 += 8) {
        bf16x8 ek;
#pragma unroll
        for (int j = 0; j < 8; j++) {
            float e = __expf(qv[d0 + j] - m);
            s += e;
            ek[j] = (__bf16)e;
        }
        *(bf16x8*)&sp[t * SPS + d0] = ek;
    }
    sinv[t] = 1.0f / s;
    __syncthreads();

    const int wave = t >> 6, lane = t & 63;
    const int wm = wave * 64;
    const int fr = lane & 15, kq = (lane >> 4) * 8;
    f32x4 acc[4][4];
#pragma unroll
    for (int i = 0; i < 4; i++)
#pragma unroll
        for (int j = 0; j < 4; j++) acc[i][j] = (f32x4)(0.0f);
#pragma unroll
    for (int kh = 0; kh < 2; kh++) {
        bf16x8 af[4], bfr[4];
#pragma unroll
        for (int i = 0; i < 4; i++)
            af[i] = *(const bf16x8*)&sp[(wm + i * 16 + fr) * SPS + kh * 32 + kq];
#pragma unroll
        for (int j = 0; j < 4; j++)
            bfr[j] = *(const bf16x8*)&sctx[(j * 16 + fr) * SPS + kh * 32 + kq];
#pragma unroll
        for (int i = 0; i < 4; i++)
#pragma unroll
            for (int j = 0; j < 4; j++)
                acc[i][j] = __builtin_amdgcn_mfma_f32_16x16x32_bf16(af[i], bfr[j], acc[i][j], 0, 0, 0);
    }

    __bf16* ob = qkv + (size_t)b * 1536 * L + (size_t)512 * L;
    const int col = lane & 15, rbase = (lane >> 4) * 4;
#pragma unroll
    for (int i = 0; i < 4; i++) {
#pragma unroll
        for (int r = 0; r < 4; r++) {
            const int nl = wm + i * 16 + rbase + r;
            const float inv = sinv[nl];
            const size_t rowoff = (size_t)(n0 + nl) * 512 + h * 64;
#pragma unroll
            for (int j = 0; j < 4; j++)
                ob[rowoff + j * 16 + col] = (__bf16)(acc[i][j][r] * inv);
        }
    }
}

// ---------------------------------------------------------------------------
extern "C" void kernel_launch(void* const* d_in, const int* in_sizes, int n_in,
                              void* d_out, int out_size, void* d_ws, size_t ws_size,
                              hipStream_t stream) {
    const float* x    = (const float*)d_in[0];
    const float* Wqkv = (const float*)d_in[1];
    const float* Wout = (const float*)d_in[2];
    const float* bout = (const float*)d_in[3];
    float* y = (float*)d_out;

    __bf16* qkv   = (__bf16*)d_ws;                               // 8*1536*4096 bf16
    float*  ctxp  = (float*)(qkv + (size_t)8 * 1536 * L);        // NCH*64*4096 f32
    float*  mstat = (float*)(ctxp + (size_t)NCH * 64 * 4096);    // NCH*64*64 f32
    float*  sstat = mstat + (size_t)NCH * 64 * 64;               // NCH*64*64 f32
    __bf16* ctxT  = (__bf16*)(sstat + (size_t)NCH * 64 * 64);    // 64*4096 bf16

    // qkv[b][o][l] = sum_d Wqkv[o][d] * x[b][l][d]  (f32 inputs, converted
    // in-staging; M=1536, N=4096, K=512), bf16 out
    gemm_ws2<1536, 4096, 512, float, float, __bf16><<<dim3(4096 / 256, 1536 / 256, 8), 512, 0, stream>>>(
        Wqkv, 0, x, (size_t)4096 * 512, qkv, (size_t)1536 * 4096, nullptr);

    context_local<<<dim3(NCH, 64), 256, 0, stream>>>(qkv, ctxp, mstat, sstat);
    ctx_combine<<<dim3(256), 256, 0, stream>>>(ctxp, mstat, sstat, ctxT);
    pv_fused<<<dim3(L / 256, 64), 256, 0, stream>>>(qkv, ctxT);

    // y[b][l][d] = sum_c outT[b][l][c] * Wout[d][c] + bout[d]
    // (A = outT bf16 via gload_lds; B = Wout f32 reg-staged), f32 out
    const __bf16* outT = qkv + (size_t)512 * L;
    gemm_ws2<4096, 512, 512, __bf16, float, float><<<dim3(512 / 256, 4096 / 256, 8), 512, 0, stream>>>(
        outT, (size_t)1536 * L, Wout, 0, y, (size_t)4096 * 512, bout);
}